// Round 1
// baseline (367.883 us; speedup 1.0000x reference)
//
#include <hip/hip_runtime.h>
#include <hip/hip_bf16.h>

#define L_SEQ 4096
#define NH 8
#define DH 128
#define NQB 32
#define NKB 64
#define TOPK 32
#define KCH 16

typedef __bf16 bf16x8 __attribute__((ext_vector_type(8)));
typedef float floatx4 __attribute__((ext_vector_type(4)));

static_assert(sizeof(bf16x8) == 16, "bf16x8 must be 16B");

// ---------------- K -> bf16 [h][l][d] ----------------
__global__ __launch_bounds__(256) void k_convert_k(const float* __restrict__ kin,
                                                   __bf16* __restrict__ kb)
{
    int t = blockIdx.x * 256 + threadIdx.x;      // 524288 threads, 8 elems each
    long base = (long)t * 8;                     // flat [l][h][d]
    int d  = (int)(base & 127);
    int lh = (int)(base >> 7);
    int h  = lh & 7;
    int l  = lh >> 3;
    const float4* s = (const float4*)(kin + base);
    float4 a = s[0], b = s[1];
    bf16x8 o;
    o[0] = (__bf16)a.x; o[1] = (__bf16)a.y; o[2] = (__bf16)a.z; o[3] = (__bf16)a.w;
    o[4] = (__bf16)b.x; o[5] = (__bf16)b.y; o[6] = (__bf16)b.z; o[7] = (__bf16)b.w;
    *(bf16x8*)(kb + ((long)(h * L_SEQ + l)) * DH + d) = o;
}

// ---------------- V -> bf16 transposed [h][d][l] ----------------
__global__ __launch_bounds__(256) void k_transpose_v(const float* __restrict__ vin,
                                                     __bf16* __restrict__ vt)
{
    __shared__ float tile[64][129];
    const int lb = blockIdx.x, h = blockIdx.y, t = threadIdx.x;
    {
        const int r = t >> 2, seg = (t & 3) * 32;
        const float* src = vin + ((long)((lb * 64 + r) * NH + h)) * DH + seg;
#pragma unroll
        for (int j = 0; j < 8; ++j) {
            float4 x = ((const float4*)src)[j];
            float* dstp = &tile[r][seg + 4 * j];
            dstp[0] = x.x; dstp[1] = x.y; dstp[2] = x.z; dstp[3] = x.w;
        }
    }
    __syncthreads();
    {
        const int d = t >> 1, lh2 = (t & 1) * 32;
        bf16x8 ov[4];
#pragma unroll
        for (int i = 0; i < 32; ++i) ov[i >> 3][i & 7] = (__bf16)tile[lh2 + i][d];
        bf16x8* dst = (bf16x8*)(vt + ((long)(h * DH + d)) * L_SEQ + lb * 64 + lh2);
#pragma unroll
        for (int j = 0; j < 4; ++j) dst[j] = ov[j];
    }
}

// ---------------- block pooling: pks[h][kb][d] = sum over 64 rows; pq[h][qb][d] = sum over 128 ----------------
__global__ __launch_bounds__(128) void k_pool(const float* __restrict__ q,
                                              const float* __restrict__ k,
                                              float* __restrict__ pq,
                                              float* __restrict__ pks)
{
    const int y = blockIdx.x, h = blockIdx.y, d = threadIdx.x;
    if (y < NKB) {
        float acc = 0.f;
        const int l0 = y * 64;
        for (int r = 0; r < 64; ++r) acc += k[((long)((l0 + r) * NH + h)) * DH + d];
        pks[((long)(h * NKB + y)) * DH + d] = acc;
    } else {
        const int qb = y - NKB;
        float acc = 0.f;
        const int l0 = qb * 128;
        for (int r = 0; r < 128; ++r) acc += q[((long)((l0 + r) * NH + h)) * DH + d];
        pq[((long)(h * NQB + qb)) * DH + d] = acc;
    }
}

// ---------------- routing: rank-based top-32 (mean_k offset is rank-invariant) ----------------
__global__ __launch_bounds__(64) void k_route(const float* __restrict__ pq,
                                              const float* __restrict__ pks,
                                              int* __restrict__ lut)
{
    __shared__ float qv[128];
    __shared__ float sc[64];
    const int qi = blockIdx.x, h = blockIdx.y, j = threadIdx.x;
    qv[j]      = pq[((long)(h * NQB + qi)) * DH + j];
    qv[j + 64] = pq[((long)(h * NQB + qi)) * DH + j + 64];
    __syncthreads();
    const float* pr = pks + ((long)(h * NKB + j)) * DH;
    float s = 0.f;
    for (int d = 0; d < 128; ++d) s += qv[d] * pr[d];
    sc[j] = s;
    __syncthreads();
    int rank = 0;
    for (int j2 = 0; j2 < 64; ++j2) {
        float o = sc[j2];
        rank += (o > s) || (o == s && j2 < j);
    }
    if (rank < TOPK) lut[(h * NQB + qi) * TOPK + rank] = j;
}

// ---------------- kv partials: kvp[h][ch][c][d] = sum_l fk[l][c]*v[l][d] over 256 rows ----------------
__global__ __launch_bounds__(256) void k_kvpart(const float* __restrict__ kin,
                                                const float* __restrict__ vin,
                                                float* __restrict__ kvp,
                                                float* __restrict__ ksp)
{
    __shared__ float fk[32][132];
    __shared__ float vv[32][132];
    const int ch = blockIdx.x, h = blockIdx.y, t = threadIdx.x;
    const int ci = t & 15, di = t >> 4;
    float acc[8][8];
#pragma unroll
    for (int i = 0; i < 8; ++i)
#pragma unroll
        for (int j = 0; j < 8; ++j) acc[i][j] = 0.f;
    float ksacc[8] = {0.f, 0.f, 0.f, 0.f, 0.f, 0.f, 0.f, 0.f};
    const int lr = t >> 3, cseg = (t & 7) * 16;

    for (int sub = 0; sub < 8; ++sub) {
        const int l0 = ch * 256 + sub * 32;
        __syncthreads();   // protect LDS from previous sub-iteration readers
        {
            const float4* ksrc = (const float4*)(kin + ((long)((l0 + lr) * NH + h)) * DH + cseg);
            const float4* vsrc = (const float4*)(vin + ((long)((l0 + lr) * NH + h)) * DH + cseg);
            float4* kd = (float4*)&fk[lr][cseg];
            float4* vd = (float4*)&vv[lr][cseg];
#pragma unroll
            for (int j = 0; j < 4; ++j) { kd[j] = ksrc[j]; vd[j] = vsrc[j]; }
        }
        __syncthreads();
        if (t < 32) {   // per-row softmax of fk
            float mx = -__builtin_inff();
            for (int c = 0; c < 128; ++c) mx = fmaxf(mx, fk[t][c]);
            float sm = 0.f;
            for (int c = 0; c < 128; ++c) { float e = __expf(fk[t][c] - mx); fk[t][c] = e; sm += e; }
            float inv = 1.f / sm;
            for (int c = 0; c < 128; ++c) fk[t][c] *= inv;
        }
        __syncthreads();
        for (int l = 0; l < 32; ++l) {
            float4 a0 = *(const float4*)&fk[l][ci * 8];
            float4 a1 = *(const float4*)&fk[l][ci * 8 + 4];
            float4 b0 = *(const float4*)&vv[l][di * 8];
            float4 b1 = *(const float4*)&vv[l][di * 8 + 4];
            float av[8] = {a0.x, a0.y, a0.z, a0.w, a1.x, a1.y, a1.z, a1.w};
            float bv[8] = {b0.x, b0.y, b0.z, b0.w, b1.x, b1.y, b1.z, b1.w};
#pragma unroll
            for (int i = 0; i < 8; ++i)
#pragma unroll
                for (int j = 0; j < 8; ++j) acc[i][j] += av[i] * bv[j];
            if (di == 0) {
#pragma unroll
                for (int i = 0; i < 8; ++i) ksacc[i] += av[i];
            }
        }
    }
    float* dst = kvp + (((long)(h * KCH + ch) * 128) + ci * 8) * 128 + di * 8;
#pragma unroll
    for (int i = 0; i < 8; ++i) {
        float4 w0 = {acc[i][0], acc[i][1], acc[i][2], acc[i][3]};
        float4 w1 = {acc[i][4], acc[i][5], acc[i][6], acc[i][7]};
        ((float4*)(dst + (long)i * 128))[0] = w0;
        ((float4*)(dst + (long)i * 128))[1] = w1;
    }
    if (di == 0) {
        float* kd2 = ksp + (h * KCH + ch) * 128 + ci * 8;
#pragma unroll
        for (int i = 0; i < 8; ++i) kd2[i] = ksacc[i];
    }
}

// ---------------- reduce partials, M[h][c][e] = sum_d kv[c][d]*W[e][d]; ksum ----------------
__global__ __launch_bounds__(128) void k_reduce_m(const float* __restrict__ kvp,
                                                  const float* __restrict__ ksp,
                                                  const float* __restrict__ w,
                                                  float* __restrict__ M,
                                                  float* __restrict__ ksum)
{
    __shared__ float kvrow[128];
    const int c = blockIdx.x, h = blockIdx.y, t = threadIdx.x;
    float acc = 0.f;
    for (int ch = 0; ch < KCH; ++ch)
        acc += kvp[(((long)(h * KCH + ch) * 128) + c) * 128 + t];
    kvrow[t] = acc;
    if (t == 0) {
        float s = 0.f;
        for (int ch = 0; ch < KCH; ++ch) s += ksp[(h * KCH + ch) * 128 + c];
        ksum[h * 128 + c] = s;
    }
    __syncthreads();
    const float* wr = w + (long)t * 128;
    float m = 0.f;
    for (int d = 0; d < 128; ++d) m += kvrow[d] * wr[d];
    M[((long)(h * 128 + c)) * 128 + t] = m;
}

// ---------------- linear apply: out[l][h][e] = fq·M[:,e]/den + b[e]  (overwrites d_out) ----------------
__global__ __launch_bounds__(256) void k_linear(const float* __restrict__ q,
                                                const float* __restrict__ M,
                                                const float* __restrict__ ksum,
                                                const float* __restrict__ bproj,
                                                float* __restrict__ out)
{
    __shared__ float fq[16][128];
    __shared__ float den[16];
    const int lb = blockIdx.x, h = blockIdx.y, t = threadIdx.x;
    const int l0 = lb * 16;
    {
        const int r = t >> 4, c0 = (t & 15) * 8;
        const float4* src = (const float4*)(q + ((long)((l0 + r) * NH + h)) * DH + c0);
        float4 a = src[0], b = src[1];
        float* dst = &fq[r][c0];
        dst[0] = a.x; dst[1] = a.y; dst[2] = a.z; dst[3] = a.w;
        dst[4] = b.x; dst[5] = b.y; dst[6] = b.z; dst[7] = b.w;
    }
    __syncthreads();
    if (t < 16) {
        float mx = -__builtin_inff();
        for (int c = 0; c < 128; ++c) mx = fmaxf(mx, fq[t][c]);
        float sm = 0.f;
        for (int c = 0; c < 128; ++c) { float e = __expf(fq[t][c] - mx); fq[t][c] = e; sm += e; }
        float inv = 1.f / sm;
        const float* ks = ksum + h * DH;
        float dd = 0.f;
        for (int c = 0; c < 128; ++c) { float v = fq[t][c] * inv; fq[t][c] = v; dd += v * ks[c]; }
        den[t] = 1e-5f + dd;
    }
    __syncthreads();
    const int e = t & 127, rg = t >> 7;
    float acc[8] = {0.f, 0.f, 0.f, 0.f, 0.f, 0.f, 0.f, 0.f};
    const float* Mh = M + (long)h * DH * DH + e;
#pragma unroll 4
    for (int c = 0; c < 128; ++c) {
        float m = Mh[(long)c * DH];
#pragma unroll
        for (int rr = 0; rr < 8; ++rr) acc[rr] += fq[rg * 8 + rr][c] * m;
    }
    const float b = bproj[e];
#pragma unroll
    for (int rr = 0; rr < 8; ++rr) {
        const int l = l0 + rg * 8 + rr;
        out[((long)(l * NH + h)) * DH + e] = acc[rr] / den[rg * 8 + rr] + b;
    }
}

// ---------------- sparse flash attention (MFMA bf16), accumulates into d_out ----------------
// MFMA 16x16x32_bf16 layouts (m89/m91/m120-verified):
//   A: lane holds A[m=lane&15][k=(lane>>4)*8 + j]
//   B: lane holds B[k=(lane>>4)*8 + j][n=lane&15]
//   C/D: lane holds D[row=(lane>>4)*4 + r][col=lane&15]
__global__ __launch_bounds__(256, 1) void k_sparse(const float* __restrict__ q,
                                                   const __bf16* __restrict__ kb16,
                                                   const __bf16* __restrict__ vt16,
                                                   const int* __restrict__ lut,
                                                   float* __restrict__ out)
{
    // strides padded so b128 reads hit the 8-cycle LDS floor (2-way max)
    __shared__ __align__(16) __bf16 Klds[64 * 136];     // [key][d]
    __shared__ __align__(16) __bf16 Vlds[128 * 72];     // [d][key]  (from pre-transposed vt16)
    __shared__ __align__(16) __bf16 Plds[4 * 32 * 72];  // per-wave [m][key]
    __shared__ int luts[TOPK];

    const int qb = blockIdx.x, h = blockIdx.y;
    const int t = threadIdx.x;
    const int w = t >> 6;
    const int lane = t & 63;
    const int l16 = lane & 15;
    const int quad = lane >> 4;

    if (t < TOPK) luts[t] = lut[(h * NQB + qb) * TOPK + t];

    // Q fragments (A-layout), kept in registers for all 32 iterations
    bf16x8 qf[2][4];
#pragma unroll
    for (int mt = 0; mt < 2; ++mt) {
        const int gl = qb * 128 + w * 32 + mt * 16 + l16;
        const float* qrow = q + ((long)(gl * NH + h)) * DH;
#pragma unroll
        for (int ks = 0; ks < 4; ++ks) {
            const float4* s2 = (const float4*)(qrow + ks * 32 + quad * 8);
            float4 a = s2[0], b = s2[1];
            bf16x8 f;
            f[0] = (__bf16)a.x; f[1] = (__bf16)a.y; f[2] = (__bf16)a.z; f[3] = (__bf16)a.w;
            f[4] = (__bf16)b.x; f[5] = (__bf16)b.y; f[6] = (__bf16)b.z; f[7] = (__bf16)b.w;
            qf[mt][ks] = f;
        }
    }

    const floatx4 vzero = {0.f, 0.f, 0.f, 0.f};
    floatx4 o_acc[2][8];
#pragma unroll
    for (int mt = 0; mt < 2; ++mt)
#pragma unroll
        for (int nt = 0; nt < 8; ++nt) o_acc[mt][nt] = vzero;
    float mstate[2][4], lstate[2][4];
#pragma unroll
    for (int mt = 0; mt < 2; ++mt)
#pragma unroll
        for (int r = 0; r < 4; ++r) { mstate[mt][r] = -__builtin_inff(); lstate[mt][r] = 0.f; }

    const float scale = 0.08838834764831845f;  // 1/sqrt(128)
    const int krow = t >> 2, kseg = t & 3;
    const int vrow = t >> 1, vseg = t & 1;
    const __bf16* kbh = kb16 + (long)h * L_SEQ * DH;
    const __bf16* vth = vt16 + (long)h * DH * L_SEQ;

    for (int it = 0; it < TOPK; ++it) {
        __syncthreads();                 // previous iter's LDS readers done
        const int kb = luts[it];
        {   // stage K tile [64][128] and V tile [128][64]
            const bf16x8* src = (const bf16x8*)(kbh + ((long)(kb * 64 + krow)) * DH + kseg * 32);
            bf16x8* dst = (bf16x8*)(Klds + krow * 136 + kseg * 32);
            dst[0] = src[0]; dst[1] = src[1]; dst[2] = src[2]; dst[3] = src[3];
            const bf16x8* vsrc = (const bf16x8*)(vth + (long)vrow * L_SEQ + kb * 64 + vseg * 32);
            bf16x8* vdst = (bf16x8*)(Vlds + vrow * 72 + vseg * 32);
            vdst[0] = vsrc[0]; vdst[1] = vsrc[1]; vdst[2] = vsrc[2]; vdst[3] = vsrc[3];
        }
        __syncthreads();

        // S = Q @ K^T  (32 rows x 64 keys per wave)
        floatx4 sfr[2][4];
#pragma unroll
        for (int mt = 0; mt < 2; ++mt)
#pragma unroll
            for (int nt = 0; nt < 4; ++nt) sfr[mt][nt] = vzero;
#pragma unroll
        for (int ks = 0; ks < 4; ++ks) {
            bf16x8 bf[4];
#pragma unroll
            for (int nt = 0; nt < 4; ++nt)
                bf[nt] = *(const bf16x8*)(Klds + (nt * 16 + l16) * 136 + ks * 32 + quad * 8);
#pragma unroll
            for (int mt = 0; mt < 2; ++mt)
#pragma unroll
                for (int nt = 0; nt < 4; ++nt)
                    sfr[mt][nt] = __builtin_amdgcn_mfma_f32_16x16x32_bf16(qf[mt][ks], bf[nt], sfr[mt][nt], 0, 0, 0);
        }

        // online softmax per row; write P (bf16) to per-wave LDS for layout turn
#pragma unroll
        for (int mt = 0; mt < 2; ++mt) {
#pragma unroll
            for (int r = 0; r < 4; ++r) {
                float s0 = sfr[mt][0][r] * scale;
                float s1 = sfr[mt][1][r] * scale;
                float s2 = sfr[mt][2][r] * scale;
                float s3 = sfr[mt][3][r] * scale;
                float vmax = fmaxf(fmaxf(s0, s1), fmaxf(s2, s3));
                vmax = fmaxf(vmax, __shfl_xor(vmax, 1));
                vmax = fmaxf(vmax, __shfl_xor(vmax, 2));
                vmax = fmaxf(vmax, __shfl_xor(vmax, 4));
                vmax = fmaxf(vmax, __shfl_xor(vmax, 8));
                const float mold = mstate[mt][r];
                const float mnew = fmaxf(mold, vmax);
                mstate[mt][r] = mnew;
                const float alpha = __expf(mold - mnew);   // exp(-inf)=0 on first iter
                float p0 = __expf(s0 - mnew);
                float p1 = __expf(s1 - mnew);
                float p2 = __expf(s2 - mnew);
                float p3 = __expf(s3 - mnew);
                float rsum = (p0 + p1) + (p2 + p3);
                rsum += __shfl_xor(rsum, 1);
                rsum += __shfl_xor(rsum, 2);
                rsum += __shfl_xor(rsum, 4);
                rsum += __shfl_xor(rsum, 8);
                lstate[mt][r] = lstate[mt][r] * alpha + rsum;
#pragma unroll
                for (int nt = 0; nt < 8; ++nt) o_acc[mt][nt][r] *= alpha;
                __bf16* pb = Plds + w * (32 * 72) + (mt * 16 + quad * 4 + r) * 72 + l16;
                pb[0]  = (__bf16)p0;
                pb[16] = (__bf16)p1;
                pb[32] = (__bf16)p2;
                pb[48] = (__bf16)p3;
            }
        }
        __syncthreads();   // drain P writes before A-layout reads

        // O += P @ V
#pragma unroll
        for (int ks2 = 0; ks2 < 2; ++ks2) {
            bf16x8 af[2];
#pragma unroll
            for (int mt = 0; mt < 2; ++mt)
                af[mt] = *(const bf16x8*)(Plds + w * (32 * 72) + (mt * 16 + l16) * 72 + ks2 * 32 + quad * 8);
#pragma unroll
            for (int nt = 0; nt < 8; ++nt) {
                bf16x8 bv = *(const bf16x8*)(Vlds + (nt * 16 + l16) * 72 + ks2 * 32 + quad * 8);
#pragma unroll
                for (int mt = 0; mt < 2; ++mt)
                    o_acc[mt][nt] = __builtin_amdgcn_mfma_f32_16x16x32_bf16(af[mt], bv, o_acc[mt][nt], 0, 0, 0);
            }
        }
    }

    // epilogue: out += O / l
#pragma unroll
    for (int mt = 0; mt < 2; ++mt) {
#pragma unroll
        for (int r = 0; r < 4; ++r) {
            const int gl = qb * 128 + w * 32 + mt * 16 + quad * 4 + r;
            const float inv = 1.0f / lstate[mt][r];
#pragma unroll
            for (int nt = 0; nt < 8; ++nt) {
                const int e = nt * 16 + l16;
                const long idx = ((long)(gl * NH + h)) * DH + e;
                out[idx] += o_acc[mt][nt][r] * inv;
            }
        }
    }
}

extern "C" void kernel_launch(void* const* d_in, const int* in_sizes, int n_in,
                              void* d_out, int out_size, void* d_ws, size_t ws_size,
                              hipStream_t stream)
{
    const float* q = (const float*)d_in[0];
    const float* k = (const float*)d_in[1];
    const float* v = (const float*)d_in[2];
    const float* w = (const float*)d_in[3];
    const float* b = (const float*)d_in[4];
    float* out = (float*)d_out;
    char* ws = (char*)d_ws;

    // workspace layout (~26.2 MB, all offsets 256B-aligned)
    __bf16* kb16 = (__bf16*)(ws + 0);          //  8,388,608  K bf16 [h][l][d]
    __bf16* vt16 = (__bf16*)(ws + 8388608);    //  8,388,608  V bf16 [h][d][l]
    float*  pq   = (float*)(ws + 16777216);    //    131,072  q block sums
    float*  pks  = (float*)(ws + 16908288);    //    262,144  k block sums
    int*    lut  = (int*)  (ws + 17170432);    //     32,768  top-32 indices
    float*  kvp  = (float*)(ws + 17203200);    //  8,388,608  kv partials
    float*  ksp  = (float*)(ws + 25591808);    //     65,536  ksum partials
    float*  ksum = (float*)(ws + 25657344);    //      4,096
    float*  M    = (float*)(ws + 25661440);    //    524,288  kv @ W^T

    k_convert_k <<<dim3(2048),    dim3(256), 0, stream>>>(k, kb16);
    k_transpose_v<<<dim3(64, 8),  dim3(256), 0, stream>>>(v, vt16);
    k_pool      <<<dim3(96, 8),   dim3(128), 0, stream>>>(q, k, pq, pks);
    k_route     <<<dim3(32, 8),   dim3(64),  0, stream>>>(pq, pks, lut);
    k_kvpart    <<<dim3(16, 8),   dim3(256), 0, stream>>>(k, v, kvp, ksp);
    k_reduce_m  <<<dim3(128, 8),  dim3(128), 0, stream>>>(kvp, ksp, w, M, ksum);
    k_linear    <<<dim3(256, 8),  dim3(256), 0, stream>>>(q, M, ksum, b, out);   // writes d_out
    k_sparse    <<<dim3(32, 8),   dim3(256), 0, stream>>>(q, kb16, vt16, lut, out); // += sparse part
}